// Round 23
// baseline (224.972 us; speedup 1.0000x reference)
//
#include <hip/hip_runtime.h>
#include <hip/hip_bf16.h>
#include <stdint.h>
#include <math.h>

#define B_ 4
#define T_ 2048
#define E_ 1024
#define H_ 16
#define D_ 64

typedef __attribute__((ext_vector_type(8))) short short8;
typedef __attribute__((ext_vector_type(4))) short short4v;
typedef __attribute__((ext_vector_type(4))) float f32x4;

#define MFMA_BF16(a, b, c) __builtin_amdgcn_mfma_f32_16x16x32_bf16((a), (b), (c), 0, 0, 0)

__device__ __forceinline__ unsigned short f2bf(float f) {
  union { float f; unsigned u; } v; v.f = f;
  unsigned r = v.u + 0x7FFFu + ((v.u >> 16) & 1u);  // RNE
  return (unsigned short)(r >> 16);
}

#define GLOAD_LDS16(g, l)                                                        \
  __builtin_amdgcn_global_load_lds((const __attribute__((address_space(1))) void*)(g), \
                                   (__attribute__((address_space(3))) void*)(l), 16, 0, 0)

// ---------------- fp32 -> bf16 convert: x + 4 weights in ONE launch ----------
__global__ __launch_bounds__(256) void cvt_all(const float* __restrict__ x,
                                               const float* __restrict__ w0,
                                               const float* __restrict__ w1,
                                               const float* __restrict__ w2,
                                               const float* __restrict__ w3,
                                               unsigned short* __restrict__ xb,
                                               unsigned short* __restrict__ wb) {
  const int NX8 = 1048576;  // XE/8
  int i = blockIdx.x * blockDim.x + threadIdx.x;
  const float* src;
  unsigned short* dst;
  size_t off;
  if (i < NX8) {
    src = x; dst = xb; off = (size_t)i * 8;
  } else {
    int j = i - NX8;
    int which = j >> 17;             // WE/8 = 2^17
    int o = j & 131071;
    src = (which == 0) ? w0 : (which == 1) ? w1 : (which == 2) ? w2 : w3;
    dst = wb + ((size_t)which << 20);
    off = (size_t)o * 8;
  }
  const float4* p = (const float4*)(src + off);
  float4 a = p[0], b = p[1];
  short8 r;
  r[0] = (short)f2bf(a.x); r[1] = (short)f2bf(a.y);
  r[2] = (short)f2bf(a.z); r[3] = (short)f2bf(a.w);
  r[4] = (short)f2bf(b.x); r[5] = (short)f2bf(b.y);
  r[6] = (short)f2bf(b.z); r[7] = (short)f2bf(b.w);
  *(short8*)(dst + off) = r;
}

// =============== 128x256 2-phase pipelined GEMM template (r18, proven) =======
#define GEMM2_BODY(A_PTR, B_PTR)                                                  \
  const int K = E_;                                                               \
  const int NT = 16;                                                              \
  const int tid = threadIdx.x;                                                    \
  const int wid = tid >> 6;                                                       \
  const int lane = tid & 63;                                                      \
  const int lr = lane & 15;                                                       \
  const int lk = lane >> 4;                                                       \
  const int wm = wid >> 2, wn = wid & 3;                                          \
  const int srow = lane >> 3;                                                     \
  const int scol = ((lane & 7) ^ srow) * 8;                                       \
  const int rswz = (lr & 7) << 4;                                                 \
  const int kofs0 = (lk * 16) ^ rswz;                                             \
  const int kofs1 = (64 + lk * 16) ^ rswz;                                        \
  f32x4 acc[4][4] = {};                                                           \
  short8 af[4][2], bf0[2][2], bf1[2][2];                                          \
  auto stageA = [&](int tau) {                                                    \
    char* dst = lds + (tau & 1) * 49152 + wid * 1024;                             \
    const unsigned short* src = (A_PTR) + (size_t)(m0 + wid * 8 + srow) * K +     \
                                tau * 64 + scol;                                  \
    GLOAD_LDS16(src, dst);                                                        \
    GLOAD_LDS16(src + (size_t)64 * K, dst + 8192);                                \
  };                                                                              \
  auto stageB = [&](int tau) {                                                    \
    char* dst = lds + (tau & 1) * 49152 + 16384 + wid * 1024;                     \
    const unsigned short* src = (B_PTR) + (size_t)(n0 + wid * 8 + srow) * K +     \
                                tau * 64 + scol;                                  \
    GLOAD_LDS16(src, dst);                                                        \
    GLOAD_LDS16(src + (size_t)64 * K, dst + 8192);                                \
    GLOAD_LDS16(src + (size_t)128 * K, dst + 16384);                              \
    GLOAD_LDS16(src + (size_t)192 * K, dst + 24576);                              \
  };                                                                              \
  stageB(0); stageA(0); stageB(1);                                                \
  asm volatile("s_waitcnt vmcnt(4)" ::: "memory");                                \
  __builtin_amdgcn_s_barrier();                                                   \
  for (int t = 0; t < NT; ++t) {                                                  \
    char* bufA = lds + (t & 1) * 49152;                                           \
    char* bufB = bufA + 16384;                                                    \
    _Pragma("unroll")                                                             \
    for (int i = 0; i < 4; ++i) {                                                 \
      int row = wm * 64 + i * 16 + lr;                                            \
      af[i][0] = *(const short8*)(bufA + row * 128 + kofs0);                      \
      af[i][1] = *(const short8*)(bufA + row * 128 + kofs1);                      \
    }                                                                             \
    _Pragma("unroll")                                                             \
    for (int i = 0; i < 2; ++i) {                                                 \
      int row0 = wn * 64 + i * 16 + lr;                                           \
      int row1 = wn * 64 + (2 + i) * 16 + lr;                                     \
      bf0[i][0] = *(const short8*)(bufB + row0 * 128 + kofs0);                    \
      bf0[i][1] = *(const short8*)(bufB + row0 * 128 + kofs1);                    \
      bf1[i][0] = *(const short8*)(bufB + row1 * 128 + kofs0);                    \
      bf1[i][1] = *(const short8*)(bufB + row1 * 128 + kofs1);                    \
    }                                                                             \
    if (t + 1 < NT) stageA(t + 1);                                                \
    __builtin_amdgcn_s_barrier();                                                 \
    asm volatile("s_waitcnt lgkmcnt(0)" ::: "memory");                            \
    __builtin_amdgcn_sched_barrier(0);                                            \
    __builtin_amdgcn_s_setprio(1);                                                \
    _Pragma("unroll")                                                             \
    for (int i = 0; i < 4; ++i)                                                   \
      _Pragma("unroll")                                                           \
      for (int jn = 0; jn < 2; ++jn) {                                            \
        acc[i][jn] = MFMA_BF16(af[i][0], bf0[jn][0], acc[i][jn]);                 \
        acc[i][jn] = MFMA_BF16(af[i][1], bf0[jn][1], acc[i][jn]);                 \
      }                                                                           \
    __builtin_amdgcn_s_setprio(0);                                                \
    __builtin_amdgcn_s_barrier();                                                 \
    if (t + 2 < NT) stageB(t + 2);                                                \
    __builtin_amdgcn_s_setprio(1);                                                \
    _Pragma("unroll")                                                             \
    for (int i = 0; i < 4; ++i)                                                   \
      _Pragma("unroll")                                                           \
      for (int jn = 0; jn < 2; ++jn) {                                            \
        acc[i][2 + jn] = MFMA_BF16(af[i][0], bf1[jn][0], acc[i][2 + jn]);         \
        acc[i][2 + jn] = MFMA_BF16(af[i][1], bf1[jn][1], acc[i][2 + jn]);         \
      }                                                                           \
    __builtin_amdgcn_s_setprio(0);                                                \
    if (t < NT - 2) asm volatile("s_waitcnt vmcnt(4)" ::: "memory");              \
    else            asm volatile("s_waitcnt vmcnt(0)" ::: "memory");              \
    __builtin_amdgcn_s_barrier();                                                 \
  }

// ---------------- QKV GEMM (768 blocks = 3 exact rounds at 1 blk/CU) ---------
__global__ __launch_bounds__(512) void gemm_qkv2(const unsigned short* __restrict__ A,
                                                 const unsigned short* __restrict__ Wq,
                                                 const unsigned short* __restrict__ Wk,
                                                 const unsigned short* __restrict__ Wv,
                                                 unsigned short* __restrict__ Qo,
                                                 unsigned short* __restrict__ Ko,
                                                 unsigned short* __restrict__ Vo) {
  __shared__ __align__(16) char lds[98304];
  const int bid = blockIdx.x;
  const int xcd = bid & 7;
  const int p = bid >> 3;               // 0..95
  const int m0 = (xcd * 8 + (p & 7)) * 128;
  const int j = p >> 3;                 // 0..11
  const int n0 = (j & 3) * 256;
  const int sel = j >> 2;
  const unsigned short* Bm = (sel == 0) ? Wq : (sel == 1) ? Wk : Wv;

  GEMM2_BODY(A, Bm)

  unsigned short* outp = (sel == 0) ? Qo : (sel == 1) ? Ko : Vo;
#pragma unroll
  for (int mi = 0; mi < 4; ++mi)
#pragma unroll
    for (int ni = 0; ni < 4; ++ni) {
      int row0 = m0 + wm * 64 + mi * 16 + lk * 4;
      int col = n0 + wn * 64 + ni * 16 + lr;
      int b = row0 >> 11, t0 = row0 & (T_ - 1), h = col >> 6, d = col & (D_ - 1);
      if (sel == 2) {
        short4v vv;
#pragma unroll
        for (int r = 0; r < 4; ++r) vv[r] = (short)f2bf(acc[mi][ni][r]);
        *(short4v*)&outp[(((size_t)(b * H_ + h)) * D_ + d) * T_ + t0] = vv;  // [BH][D][T]
      } else {
#pragma unroll
        for (int r = 0; r < 4; ++r)
          outp[(((size_t)(b * H_ + h)) * T_ + t0 + r) * D_ + d] = f2bf(acc[mi][ni][r]);
      }
    }
}

// ---------------- out-proj GEMM (256 blocks = exactly 1/CU) ------------------
__global__ __launch_bounds__(512) void gemm_out2(const unsigned short* __restrict__ A,
                                                 const unsigned short* __restrict__ Wout,
                                                 float* __restrict__ outp,
                                                 const float* __restrict__ bias) {
  __shared__ __align__(16) char lds[98304];
  const int bid = blockIdx.x;
  const int xcd = bid & 7;
  const int p = bid >> 3;               // 0..31
  const int m0 = (xcd * 8 + (p & 7)) * 128;
  const int n0 = (p >> 3) * 256;

  GEMM2_BODY(A, Wout)

#pragma unroll
  for (int mi = 0; mi < 4; ++mi)
#pragma unroll
    for (int ni = 0; ni < 4; ++ni) {
      int row0 = m0 + wm * 64 + mi * 16 + lk * 4;
      int col = n0 + wn * 64 + ni * 16 + lr;
      float bv = bias[col];
#pragma unroll
      for (int r = 0; r < 4; ++r)
        outp[(size_t)(row0 + r) * E_ + col] = acc[mi][ni][r] + bv;
    }
}

// ---------------- fused causal flash attention (8-wave, lagged sigma-PV) -----
// r22 structure (256 blocks x 512 thr, intrinsic 36-tile pairing, 32KB K/V
// LDS, sigma-register P) + r11's lagged PV: PV(t-1) runs as pure-register
// MFMA between rowmax(t) and rescale(t), mixing MFMA into the VALU phase
// (the serial chain that bound r19-r22 at ~94us). V(t) is read during tile t
// (buffer valid) and consumed at t+1 — no hazard with stage(t+1) (other
// parity). Parity-duplicated body keeps all fragment indices static.
__global__ __launch_bounds__(512) void attn_fused8(const unsigned short* __restrict__ Q,
                                                   const unsigned short* __restrict__ K,
                                                   const unsigned short* __restrict__ VT,
                                                   unsigned short* __restrict__ ctx) {
  __shared__ __align__(16) char kvb[2][16384];  // [buf][K 8K | V 8K]
  const int tid = threadIdx.x;
  const int wid = tid >> 6;
  const int lane = tid & 63;
  const int lr = lane & 15;
  const int lk = lane >> 4;

  // 256 = 8 xcd x 8 heads x 4 pair-ids
  const int bid = blockIdx.x;
  const int xcd = bid & 7;
  const int p = bid >> 3;            // 0..31
  const int bh = xcd * 8 + (p & 7);
  const int g = p >> 3;              // 0..3

  const unsigned short* Qh = Q + (size_t)bh * T_ * D_;
  const unsigned short* Kh = K + (size_t)bh * T_ * D_;
  const unsigned short* Vh = VT + (size_t)bh * T_ * D_;  // [D][T]

  const float SC = 0.125f * 1.44269504089f;  // 1/sqrt(D) * log2(e)

  // staging: thread stages one 16B chunk of K and one of V per tile
  const int srow = tid >> 3;                       // 0..63
  const int scol = ((tid & 7) ^ (srow & 7)) * 8;   // pre-swizzled col (elems)
  const int rswz = (lr & 7) << 4;                  // read-side XOR (bytes)

  auto stage = [&](int t) {
    char* dst = kvb[t & 1] + tid * 16;
    GLOAD_LDS16(Kh + (size_t)(t * 64 + srow) * D_ + scol, dst);
    GLOAD_LDS16(Vh + (size_t)srow * T_ + t * 64 + scol, dst + 8192);
  };

  short8 vones;
#pragma unroll
  for (int jj = 0; jj < 8; ++jj) vones[jj] = (short)0x3F80;  // bf16 1.0

  const int b = bh >> 4, h2 = bh & 15;

  for (int pass = 0; pass < 2; ++pass) {
    const int Qb = pass ? g : (7 - g);
    const int q0w = Qb * 256 + wid * 32;
    const int diag = q0w >> 6;       // wave's diagonal kv-tile
    const int ql0 = (wid & 1) * 32;  // q-local base within diag tile
    const int NTb = 4 * Qb + 4;      // pass trip count

    // Q as B-operand: col=q=lr, k=d
    short8 qf[2][2];
#pragma unroll
    for (int a = 0; a < 2; ++a)
#pragma unroll
      for (int kb = 0; kb < 2; ++kb)
        qf[a][kb] = *(const short8*)&Qh[(size_t)(q0w + a * 16 + lr) * D_ + kb * 32 + lk * 8];

    f32x4 o[2][4] = {};
    f32x4 lsum[2] = {};
    float mrun[2] = {-1e30f, -1e30f};

    // two named P/V register sets (parity ping-pong; all indices static)
    short8 pfA[2][2], vrA[2][4];
    short8 pfB[2][2], vrB[2][4];

    // register-only PV (lagged): O += P V; lsum += P * ones
    auto pvreg = [&](short8(&pf)[2][2], short8(&vr)[2][4]) {
#pragma unroll
      for (int h = 0; h < 2; ++h) {
#pragma unroll
        for (int nd = 0; nd < 4; ++nd) {
          o[0][nd] = MFMA_BF16(pf[0][h], vr[h][nd], o[0][nd]);
          o[1][nd] = MFMA_BF16(pf[1][h], vr[h][nd], o[1][nd]);
        }
        lsum[0] = MFMA_BF16(pf[0][h], vones, lsum[0]);
        lsum[1] = MFMA_BF16(pf[1][h], vones, lsum[1]);
      }
    };

    // per-tile body; pfC/vrC = this tile's sets, pfP/vrP = previous tile's.
    auto body = [&](int t, bool doPV,
                    short8(&pfC)[2][2], short8(&vrC)[2][4],
                    short8(&pfP)[2][2], short8(&vrP)[2][4]) {
      char* kb_ = kvb[t & 1];
      char* vb_ = kvb[t & 1] + 8192;

      // K fragments from LDS
      short8 kf[2][4];
#pragma unroll
      for (int kb = 0; kb < 2; ++kb)
#pragma unroll
        for (int n = 0; n < 4; ++n)
          kf[kb][n] = *(const short8*)(kb_ + (n * 16 + lr) * 128 + ((kb * 64 + lk * 16) ^ rswz));

      // V fragments (sigma k-slot layout), consumed NEXT tile
#pragma unroll
      for (int h = 0; h < 2; ++h)
#pragma unroll
        for (int nd = 0; nd < 4; ++nd) {
          const char* vrow = vb_ + (nd * 16 + lr) * 128;
          *(uint2*)&vrC[h][nd] = *(const uint2*)(vrow + ((h * 64 + lk * 8) ^ rswz));
          *((uint2*)&vrC[h][nd] + 1) = *(const uint2*)(vrow + ((h * 64 + 32 + lk * 8) ^ rswz));
        }

      // S^T = K Q^T
      f32x4 st[2][4] = {};
#pragma unroll
      for (int kb = 0; kb < 2; ++kb)
#pragma unroll
        for (int a = 0; a < 2; ++a)
#pragma unroll
          for (int n = 0; n < 4; ++n)
            st[a][n] = MFMA_BF16(kf[kb][n], qf[a][kb], st[a][n]);

      if (t == diag) {  // causal mask
#pragma unroll
        for (int a = 0; a < 2; ++a)
#pragma unroll
          for (int n = 0; n < 4; ++n)
#pragma unroll
            for (int r = 0; r < 4; ++r)
              if (n * 16 + lk * 4 + r > ql0 + a * 16 + lr) st[a][n][r] = -3e38f;
      }

      // row max (in-lane tree + 2 shuffles)
      float pm[2];
#pragma unroll
      for (int a = 0; a < 2; ++a) {
        float m0 = fmaxf(fmaxf(st[a][0][0], st[a][1][0]), fmaxf(st[a][2][0], st[a][3][0]));
        float m1 = fmaxf(fmaxf(st[a][0][1], st[a][1][1]), fmaxf(st[a][2][1], st[a][3][1]));
        float m2 = fmaxf(fmaxf(st[a][0][2], st[a][1][2]), fmaxf(st[a][2][2], st[a][3][2]));
        float m3 = fmaxf(fmaxf(st[a][0][3], st[a][1][3]), fmaxf(st[a][2][3], st[a][3][3]));
        float mx = fmaxf(fmaxf(m0, m1), fmaxf(m2, m3));
        mx = fmaxf(mx, __shfl_xor(mx, 16));
        mx = fmaxf(mx, __shfl_xor(mx, 32));
        pm[a] = mx * SC;
      }
      float need = fmaxf(pm[0] - mrun[0], pm[1] - mrun[1]);

      // lagged PV(t-1): absorbs at OLD scale, overlaps softmax VALU
      if (doPV) pvreg(pfP, vrP);

      if (__any(need > 8.f)) {  // defer-max rescale (rare)
#pragma unroll
        for (int a = 0; a < 2; ++a) {
          float mnew = fmaxf(mrun[a], pm[a]);
          float sc = exp2f(mrun[a] - mnew);
          mrun[a] = mnew;
#pragma unroll
          for (int r = 0; r < 4; ++r) {
            float sco = __shfl(sc, (lane & 48) | (lk * 4 + r));
            lsum[a][r] *= sco;
#pragma unroll
            for (int nd = 0; nd < 4; ++nd) o[a][nd][r] *= sco;
          }
        }
      }

      // P = exp2(S*SC - m): pack in-register to sigma A-fragments
#pragma unroll
      for (int a = 0; a < 2; ++a) {
        f32x4 pt[4];
#pragma unroll
        for (int n = 0; n < 4; ++n)
#pragma unroll
          for (int r = 0; r < 4; ++r)
            pt[n][r] = exp2f(fmaf(st[a][n][r], SC, -mrun[a]));
#pragma unroll
        for (int h = 0; h < 2; ++h) {
          float2 x01, x23, y01, y23;
          x01.x = pt[2 * h][0];     x01.y = pt[2 * h][1];
          x23.x = pt[2 * h][2];     x23.y = pt[2 * h][3];
          y01.x = pt[2 * h + 1][0]; y01.y = pt[2 * h + 1][1];
          y23.x = pt[2 * h + 1][2]; y23.y = pt[2 * h + 1][3];
          __hip_bfloat162 b0 = __float22bfloat162_rn(x01);
          __hip_bfloat162 b1 = __float22bfloat162_rn(x23);
          __hip_bfloat162 b2 = __float22bfloat162_rn(y01);
          __hip_bfloat162 b3 = __float22bfloat162_rn(y23);
          unsigned* w = (unsigned*)&pfC[a][h];
          w[0] = *(unsigned*)&b0;
          w[1] = *(unsigned*)&b1;
          w[2] = *(unsigned*)&b2;
          w[3] = *(unsigned*)&b3;
        }
      }
    };

    stage(0);
    asm volatile("s_waitcnt vmcnt(0)" ::: "memory");
    __builtin_amdgcn_s_barrier();

    for (int t = 0; t < NTb; ++t) {
      if (t + 1 < NTb) stage(t + 1);  // other parity buffer

      if (t <= diag) {
        if (t & 1) body(t, t > 0, pfB, vrB, pfA, vrA);
        else       body(t, t > 0, pfA, vrA, pfB, vrB);
      }

      asm volatile("s_waitcnt vmcnt(0)" ::: "memory");  // stage(t+1) landed
      __builtin_amdgcn_s_barrier();
    }

    // epilogue: PV of the diagonal tile (last computed)
    if (diag & 1) pvreg(pfB, vrB);
    else          pvreg(pfA, vrA);

#pragma unroll
    for (int a = 0; a < 2; ++a)
#pragma unroll
      for (int r = 0; r < 4; ++r) {
        float inv = 1.0f / lsum[a][r];
        int tq = q0w + a * 16 + lk * 4 + r;
#pragma unroll
        for (int nd = 0; nd < 4; ++nd)
          ctx[((size_t)b * T_ + tq) * E_ + h2 * D_ + nd * 16 + lr] = f2bf(o[a][nd][r] * inv);
      }
  }
}

// ---------------- launcher ----------------
extern "C" void kernel_launch(void* const* d_in, const int* in_sizes, int n_in,
                              void* d_out, int out_size, void* d_ws, size_t ws_size,
                              hipStream_t stream) {
  const float* x    = (const float*)d_in[0];
  const float* Wq   = (const float*)d_in[1];
  const float* Wk   = (const float*)d_in[2];
  const float* Wv   = (const float*)d_in[3];
  const float* Wout = (const float*)d_in[4];
  const float* bout = (const float*)d_in[5];
  float* out = (float*)d_out;

  const size_t MT = (size_t)B_ * T_;      // 8192
  const size_t XE = MT * E_;              // 8,388,608
  const size_t WE = (size_t)E_ * E_;      // 1,048,576

  size_t need = (XE * 5 + WE * 4) * sizeof(unsigned short);
  if (ws_size < need) return;

  unsigned short* xb  = (unsigned short*)d_ws;
  unsigned short* wqb = xb + XE;
  unsigned short* wkb = wqb + WE;
  unsigned short* wvb = wkb + WE;
  unsigned short* wob = wvb + WE;
  unsigned short* Qb  = wob + WE;
  unsigned short* Kb  = Qb + XE;
  unsigned short* VTb = Kb + XE;
  unsigned short* ctx = VTb + XE;

  cvt_all<<<6144, 256, 0, stream>>>(x, Wq, Wk, Wv, Wout, xb, wqb);

  gemm_qkv2<<<768, 512, 0, stream>>>(xb, wqb, wkb, wvb, Qb, Kb, VTb);

  attn_fused8<<<256, 512, 0, stream>>>(Qb, Kb, VTb, ctx);

  gemm_out2<<<256, 512, 0, stream>>>(ctx, wob, out, bout);
}

// Round 24
// 168.764 us; speedup vs baseline: 1.3331x; 1.3331x over previous
//
#include <hip/hip_runtime.h>
#include <hip/hip_bf16.h>
#include <stdint.h>
#include <math.h>

#define B_ 4
#define T_ 2048
#define E_ 1024
#define H_ 16
#define D_ 64

typedef __attribute__((ext_vector_type(8))) short short8;
typedef __attribute__((ext_vector_type(4))) short short4v;
typedef __attribute__((ext_vector_type(4))) float f32x4;

#define MFMA_BF16(a, b, c) __builtin_amdgcn_mfma_f32_16x16x32_bf16((a), (b), (c), 0, 0, 0)

__device__ __forceinline__ unsigned short f2bf(float f) {
  union { float f; unsigned u; } v; v.f = f;
  unsigned r = v.u + 0x7FFFu + ((v.u >> 16) & 1u);  // RNE
  return (unsigned short)(r >> 16);
}

#define GLOAD_LDS16(g, l)                                                        \
  __builtin_amdgcn_global_load_lds((const __attribute__((address_space(1))) void*)(g), \
                                   (__attribute__((address_space(3))) void*)(l), 16, 0, 0)

// ---------------- fp32 -> bf16 convert: x + 4 weights in ONE launch ----------
__global__ __launch_bounds__(256) void cvt_all(const float* __restrict__ x,
                                               const float* __restrict__ w0,
                                               const float* __restrict__ w1,
                                               const float* __restrict__ w2,
                                               const float* __restrict__ w3,
                                               unsigned short* __restrict__ xb,
                                               unsigned short* __restrict__ wb) {
  const int NX8 = 1048576;  // XE/8
  int i = blockIdx.x * blockDim.x + threadIdx.x;
  const float* src;
  unsigned short* dst;
  size_t off;
  if (i < NX8) {
    src = x; dst = xb; off = (size_t)i * 8;
  } else {
    int j = i - NX8;
    int which = j >> 17;             // WE/8 = 2^17
    int o = j & 131071;
    src = (which == 0) ? w0 : (which == 1) ? w1 : (which == 2) ? w2 : w3;
    dst = wb + ((size_t)which << 20);
    off = (size_t)o * 8;
  }
  const float4* p = (const float4*)(src + off);
  float4 a = p[0], b = p[1];
  short8 r;
  r[0] = (short)f2bf(a.x); r[1] = (short)f2bf(a.y);
  r[2] = (short)f2bf(a.z); r[3] = (short)f2bf(a.w);
  r[4] = (short)f2bf(b.x); r[5] = (short)f2bf(b.y);
  r[6] = (short)f2bf(b.z); r[7] = (short)f2bf(b.w);
  *(short8*)(dst + off) = r;
}

// =============== 128x256 2-phase pipelined GEMM template (r18, proven) =======
#define GEMM2_BODY(A_PTR, B_PTR)                                                  \
  const int K = E_;                                                               \
  const int NT = 16;                                                              \
  const int tid = threadIdx.x;                                                    \
  const int wid = tid >> 6;                                                       \
  const int lane = tid & 63;                                                      \
  const int lr = lane & 15;                                                       \
  const int lk = lane >> 4;                                                       \
  const int wm = wid >> 2, wn = wid & 3;                                          \
  const int srow = lane >> 3;                                                     \
  const int scol = ((lane & 7) ^ srow) * 8;                                       \
  const int rswz = (lr & 7) << 4;                                                 \
  const int kofs0 = (lk * 16) ^ rswz;                                             \
  const int kofs1 = (64 + lk * 16) ^ rswz;                                        \
  f32x4 acc[4][4] = {};                                                           \
  short8 af[4][2], bf0[2][2], bf1[2][2];                                          \
  auto stageA = [&](int tau) {                                                    \
    char* dst = lds + (tau & 1) * 49152 + wid * 1024;                             \
    const unsigned short* src = (A_PTR) + (size_t)(m0 + wid * 8 + srow) * K +     \
                                tau * 64 + scol;                                  \
    GLOAD_LDS16(src, dst);                                                        \
    GLOAD_LDS16(src + (size_t)64 * K, dst + 8192);                                \
  };                                                                              \
  auto stageB = [&](int tau) {                                                    \
    char* dst = lds + (tau & 1) * 49152 + 16384 + wid * 1024;                     \
    const unsigned short* src = (B_PTR) + (size_t)(n0 + wid * 8 + srow) * K +     \
                                tau * 64 + scol;                                  \
    GLOAD_LDS16(src, dst);                                                        \
    GLOAD_LDS16(src + (size_t)64 * K, dst + 8192);                                \
    GLOAD_LDS16(src + (size_t)128 * K, dst + 16384);                              \
    GLOAD_LDS16(src + (size_t)192 * K, dst + 24576);                              \
  };                                                                              \
  stageB(0); stageA(0); stageB(1);                                                \
  asm volatile("s_waitcnt vmcnt(4)" ::: "memory");                                \
  __builtin_amdgcn_s_barrier();                                                   \
  for (int t = 0; t < NT; ++t) {                                                  \
    char* bufA = lds + (t & 1) * 49152;                                           \
    char* bufB = bufA + 16384;                                                    \
    _Pragma("unroll")                                                             \
    for (int i = 0; i < 4; ++i) {                                                 \
      int row = wm * 64 + i * 16 + lr;                                            \
      af[i][0] = *(const short8*)(bufA + row * 128 + kofs0);                      \
      af[i][1] = *(const short8*)(bufA + row * 128 + kofs1);                      \
    }                                                                             \
    _Pragma("unroll")                                                             \
    for (int i = 0; i < 2; ++i) {                                                 \
      int row0 = wn * 64 + i * 16 + lr;                                           \
      int row1 = wn * 64 + (2 + i) * 16 + lr;                                     \
      bf0[i][0] = *(const short8*)(bufB + row0 * 128 + kofs0);                    \
      bf0[i][1] = *(const short8*)(bufB + row0 * 128 + kofs1);                    \
      bf1[i][0] = *(const short8*)(bufB + row1 * 128 + kofs0);                    \
      bf1[i][1] = *(const short8*)(bufB + row1 * 128 + kofs1);                    \
    }                                                                             \
    if (t + 1 < NT) stageA(t + 1);                                                \
    __builtin_amdgcn_s_barrier();                                                 \
    asm volatile("s_waitcnt lgkmcnt(0)" ::: "memory");                            \
    __builtin_amdgcn_sched_barrier(0);                                            \
    __builtin_amdgcn_s_setprio(1);                                                \
    _Pragma("unroll")                                                             \
    for (int i = 0; i < 4; ++i)                                                   \
      _Pragma("unroll")                                                           \
      for (int jn = 0; jn < 2; ++jn) {                                            \
        acc[i][jn] = MFMA_BF16(af[i][0], bf0[jn][0], acc[i][jn]);                 \
        acc[i][jn] = MFMA_BF16(af[i][1], bf0[jn][1], acc[i][jn]);                 \
      }                                                                           \
    __builtin_amdgcn_s_setprio(0);                                                \
    __builtin_amdgcn_s_barrier();                                                 \
    if (t + 2 < NT) stageB(t + 2);                                                \
    __builtin_amdgcn_s_setprio(1);                                                \
    _Pragma("unroll")                                                             \
    for (int i = 0; i < 4; ++i)                                                   \
      _Pragma("unroll")                                                           \
      for (int jn = 0; jn < 2; ++jn) {                                            \
        acc[i][2 + jn] = MFMA_BF16(af[i][0], bf1[jn][0], acc[i][2 + jn]);         \
        acc[i][2 + jn] = MFMA_BF16(af[i][1], bf1[jn][1], acc[i][2 + jn]);         \
      }                                                                           \
    __builtin_amdgcn_s_setprio(0);                                                \
    if (t < NT - 2) asm volatile("s_waitcnt vmcnt(4)" ::: "memory");              \
    else            asm volatile("s_waitcnt vmcnt(0)" ::: "memory");              \
    __builtin_amdgcn_s_barrier();                                                 \
  }

// ---------------- QKV GEMM (768 blocks = 3 exact rounds at 1 blk/CU) ---------
__global__ __launch_bounds__(512) void gemm_qkv2(const unsigned short* __restrict__ A,
                                                 const unsigned short* __restrict__ Wq,
                                                 const unsigned short* __restrict__ Wk,
                                                 const unsigned short* __restrict__ Wv,
                                                 unsigned short* __restrict__ Qo,
                                                 unsigned short* __restrict__ Ko,
                                                 unsigned short* __restrict__ Vo) {
  __shared__ __align__(16) char lds[98304];
  const int bid = blockIdx.x;
  const int xcd = bid & 7;
  const int p = bid >> 3;               // 0..95
  const int m0 = (xcd * 8 + (p & 7)) * 128;
  const int j = p >> 3;                 // 0..11
  const int n0 = (j & 3) * 256;
  const int sel = j >> 2;
  const unsigned short* Bm = (sel == 0) ? Wq : (sel == 1) ? Wk : Wv;

  GEMM2_BODY(A, Bm)

  unsigned short* outp = (sel == 0) ? Qo : (sel == 1) ? Ko : Vo;
#pragma unroll
  for (int mi = 0; mi < 4; ++mi)
#pragma unroll
    for (int ni = 0; ni < 4; ++ni) {
      int row0 = m0 + wm * 64 + mi * 16 + lk * 4;
      int col = n0 + wn * 64 + ni * 16 + lr;
      int b = row0 >> 11, t0 = row0 & (T_ - 1), h = col >> 6, d = col & (D_ - 1);
      if (sel == 2) {
        short4v vv;
#pragma unroll
        for (int r = 0; r < 4; ++r) vv[r] = (short)f2bf(acc[mi][ni][r]);
        *(short4v*)&outp[(((size_t)(b * H_ + h)) * D_ + d) * T_ + t0] = vv;  // [BH][D][T]
      } else {
#pragma unroll
        for (int r = 0; r < 4; ++r)
          outp[(((size_t)(b * H_ + h)) * T_ + t0 + r) * D_ + d] = f2bf(acc[mi][ni][r]);
      }
    }
}

// ---------------- out-proj GEMM (256 blocks = exactly 1/CU) ------------------
__global__ __launch_bounds__(512) void gemm_out2(const unsigned short* __restrict__ A,
                                                 const unsigned short* __restrict__ Wout,
                                                 float* __restrict__ outp,
                                                 const float* __restrict__ bias) {
  __shared__ __align__(16) char lds[98304];
  const int bid = blockIdx.x;
  const int xcd = bid & 7;
  const int p = bid >> 3;               // 0..31
  const int m0 = (xcd * 8 + (p & 7)) * 128;
  const int n0 = (p >> 3) * 256;

  GEMM2_BODY(A, Wout)

#pragma unroll
  for (int mi = 0; mi < 4; ++mi)
#pragma unroll
    for (int ni = 0; ni < 4; ++ni) {
      int row0 = m0 + wm * 64 + mi * 16 + lk * 4;
      int col = n0 + wn * 64 + ni * 16 + lr;
      float bv = bias[col];
#pragma unroll
      for (int r = 0; r < 4; ++r)
        outp[(size_t)(row0 + r) * E_ + col] = acc[mi][ni][r] + bv;
    }
}

// ---------------- fused causal flash attention (8-wave, 3-buf counted vmcnt) -
// r22 body (sigma-register P, proven, VGPR 88) + T4: K/V staged into a
// 3-buffer rotation; stage(t+2) issued at tile t; steady-state wait is
// vmcnt(2) (drains stage(t+1), leaves stage(t+2) in flight) instead of the
// per-tile vmcnt(0) drain shared by r19-r22. Race-safe: stage(t+2) writes
// buf((t+2)%3) != buf(t%3) being read; tile t-1's reads of that buffer all
// completed before its end-of-tile barrier (values consumed by MFMA).
__global__ __launch_bounds__(512) void attn_fused8(const unsigned short* __restrict__ Q,
                                                   const unsigned short* __restrict__ K,
                                                   const unsigned short* __restrict__ VT,
                                                   unsigned short* __restrict__ ctx) {
  __shared__ __align__(16) char kvb[3][16384];  // [buf][K 8K | V 8K]
  const int tid = threadIdx.x;
  const int wid = tid >> 6;
  const int lane = tid & 63;
  const int lr = lane & 15;
  const int lk = lane >> 4;

  // 256 = 8 xcd x 8 heads x 4 pair-ids
  const int bid = blockIdx.x;
  const int xcd = bid & 7;
  const int p = bid >> 3;            // 0..31
  const int bh = xcd * 8 + (p & 7);
  const int g = p >> 3;              // 0..3

  const unsigned short* Qh = Q + (size_t)bh * T_ * D_;
  const unsigned short* Kh = K + (size_t)bh * T_ * D_;
  const unsigned short* Vh = VT + (size_t)bh * T_ * D_;  // [D][T]

  const float SC = 0.125f * 1.44269504089f;  // 1/sqrt(D) * log2(e)

  // staging: thread stages one 16B chunk of K and one of V per tile
  const int srow = tid >> 3;                       // 0..63
  const int scol = ((tid & 7) ^ (srow & 7)) * 8;   // pre-swizzled col (elems)
  const int rswz = (lr & 7) << 4;                  // read-side XOR (bytes)

  auto stage = [&](int t, int bi) {
    char* dst = kvb[bi] + tid * 16;
    GLOAD_LDS16(Kh + (size_t)(t * 64 + srow) * D_ + scol, dst);
    GLOAD_LDS16(Vh + (size_t)srow * T_ + t * 64 + scol, dst + 8192);
  };

  short8 vones;
#pragma unroll
  for (int jj = 0; jj < 8; ++jj) vones[jj] = (short)0x3F80;  // bf16 1.0

  const int b = bh >> 4, h2 = bh & 15;

  for (int pass = 0; pass < 2; ++pass) {
    const int Qb = pass ? g : (7 - g);
    const int q0w = Qb * 256 + wid * 32;
    const int diag = q0w >> 6;       // wave's diagonal kv-tile
    const int ql0 = (wid & 1) * 32;  // q-local base within diag tile
    const int NTb = 4 * Qb + 4;      // pass trip count

    // Q as B-operand: col=q=lr, k=d
    short8 qf[2][2];
#pragma unroll
    for (int a = 0; a < 2; ++a)
#pragma unroll
      for (int kb = 0; kb < 2; ++kb)
        qf[a][kb] = *(const short8*)&Qh[(size_t)(q0w + a * 16 + lr) * D_ + kb * 32 + lk * 8];

    f32x4 o[2][4] = {};
    f32x4 lsum[2] = {};
    float mrun[2] = {-1e30f, -1e30f};

    // prologue: stage tiles 0,1 into bufs 0,1; wait for buf0 only (vmcnt(2))
    stage(0, 0);
    stage(1, 1);
    asm volatile("s_waitcnt vmcnt(2)" ::: "memory");
    __builtin_amdgcn_s_barrier();

    int cur = 0;   // t % 3
    int nxt2 = 2;  // (t+2) % 3
    for (int t = 0; t < NTb; ++t) {
      if (t + 2 < NTb) stage(t + 2, nxt2);

      if (t <= diag) {
        char* kb_ = kvb[cur];
        char* vb_ = kvb[cur] + 8192;

        // K fragments from LDS (2-way conflict = free)
        short8 kf[2][4];
#pragma unroll
        for (int kb = 0; kb < 2; ++kb)
#pragma unroll
          for (int n = 0; n < 4; ++n)
            kf[kb][n] = *(const short8*)(kb_ + (n * 16 + lr) * 128 + ((kb * 64 + lk * 16) ^ rswz));

        // V fragments with sigma k-slot layout (two b64 LDS reads / fragment)
        short8 vreg[2][4];
#pragma unroll
        for (int h = 0; h < 2; ++h)
#pragma unroll
          for (int nd = 0; nd < 4; ++nd) {
            const char* vrow = vb_ + (nd * 16 + lr) * 128;
            *(uint2*)&vreg[h][nd] = *(const uint2*)(vrow + ((h * 64 + lk * 8) ^ rswz));
            *((uint2*)&vreg[h][nd] + 1) = *(const uint2*)(vrow + ((h * 64 + 32 + lk * 8) ^ rswz));
          }

        // S^T = K Q^T
        f32x4 st[2][4] = {};
#pragma unroll
        for (int kb = 0; kb < 2; ++kb)
#pragma unroll
          for (int a = 0; a < 2; ++a)
#pragma unroll
            for (int n = 0; n < 4; ++n)
              st[a][n] = MFMA_BF16(kf[kb][n], qf[a][kb], st[a][n]);

        if (t == diag) {  // causal mask
#pragma unroll
          for (int a = 0; a < 2; ++a)
#pragma unroll
            for (int n = 0; n < 4; ++n)
#pragma unroll
              for (int r = 0; r < 4; ++r)
                if (n * 16 + lk * 4 + r > ql0 + a * 16 + lr) st[a][n][r] = -3e38f;
        }

        // row max (in-lane tree + 2 shuffles)
        float pm[2];
#pragma unroll
        for (int a = 0; a < 2; ++a) {
          float m0 = fmaxf(fmaxf(st[a][0][0], st[a][1][0]), fmaxf(st[a][2][0], st[a][3][0]));
          float m1 = fmaxf(fmaxf(st[a][0][1], st[a][1][1]), fmaxf(st[a][2][1], st[a][3][1]));
          float m2 = fmaxf(fmaxf(st[a][0][2], st[a][1][2]), fmaxf(st[a][2][2], st[a][3][2]));
          float m3 = fmaxf(fmaxf(st[a][0][3], st[a][1][3]), fmaxf(st[a][2][3], st[a][3][3]));
          float mx = fmaxf(fmaxf(m0, m1), fmaxf(m2, m3));
          mx = fmaxf(mx, __shfl_xor(mx, 16));
          mx = fmaxf(mx, __shfl_xor(mx, 32));
          pm[a] = mx * SC;
        }
        float need = fmaxf(pm[0] - mrun[0], pm[1] - mrun[1]);

        if (__any(need > 8.f)) {  // defer-max rescale (rare)
#pragma unroll
          for (int a = 0; a < 2; ++a) {
            float mnew = fmaxf(mrun[a], pm[a]);
            float sc = exp2f(mrun[a] - mnew);
            mrun[a] = mnew;
#pragma unroll
            for (int r = 0; r < 4; ++r) {
              float sco = __shfl(sc, (lane & 48) | (lk * 4 + r));
              lsum[a][r] *= sco;
#pragma unroll
              for (int nd = 0; nd < 4; ++nd) o[a][nd][r] *= sco;
            }
          }
        }

        // P = exp2(S*SC - m): pack in-register to sigma A-fragments (no LDS)
        short8 pf[2][2];
#pragma unroll
        for (int a = 0; a < 2; ++a) {
          f32x4 pt[4];
#pragma unroll
          for (int n = 0; n < 4; ++n)
#pragma unroll
            for (int r = 0; r < 4; ++r)
              pt[n][r] = exp2f(fmaf(st[a][n][r], SC, -mrun[a]));
#pragma unroll
          for (int h = 0; h < 2; ++h) {
            float2 x01, x23, y01, y23;
            x01.x = pt[2 * h][0];     x01.y = pt[2 * h][1];
            x23.x = pt[2 * h][2];     x23.y = pt[2 * h][3];
            y01.x = pt[2 * h + 1][0]; y01.y = pt[2 * h + 1][1];
            y23.x = pt[2 * h + 1][2]; y23.y = pt[2 * h + 1][3];
            __hip_bfloat162 b0 = __float22bfloat162_rn(x01);
            __hip_bfloat162 b1 = __float22bfloat162_rn(x23);
            __hip_bfloat162 b2 = __float22bfloat162_rn(y01);
            __hip_bfloat162 b3 = __float22bfloat162_rn(y23);
            unsigned* w = (unsigned*)&pf[a][h];
            w[0] = *(unsigned*)&b0;
            w[1] = *(unsigned*)&b1;
            w[2] = *(unsigned*)&b2;
            w[3] = *(unsigned*)&b3;
          }
        }

        // O += P V ; lsum += P * ones  (pure register MFMA)
#pragma unroll
        for (int h = 0; h < 2; ++h) {
#pragma unroll
          for (int nd = 0; nd < 4; ++nd) {
            o[0][nd] = MFMA_BF16(pf[0][h], vreg[h][nd], o[0][nd]);
            o[1][nd] = MFMA_BF16(pf[1][h], vreg[h][nd], o[1][nd]);
          }
          lsum[0] = MFMA_BF16(pf[0][h], vones, lsum[0]);
          lsum[1] = MFMA_BF16(pf[1][h], vones, lsum[1]);
        }
      }

      // counted wait: ensure stage(t+1) landed; leave stage(t+2) in flight
      if (t + 2 < NTb) asm volatile("s_waitcnt vmcnt(2)" ::: "memory");
      else             asm volatile("s_waitcnt vmcnt(0)" ::: "memory");
      __builtin_amdgcn_s_barrier();

      cur = (cur == 2) ? 0 : cur + 1;
      nxt2 = (nxt2 == 2) ? 0 : nxt2 + 1;
    }

#pragma unroll
    for (int a = 0; a < 2; ++a)
#pragma unroll
      for (int r = 0; r < 4; ++r) {
        float inv = 1.0f / lsum[a][r];
        int tq = q0w + a * 16 + lk * 4 + r;
#pragma unroll
        for (int nd = 0; nd < 4; ++nd)
          ctx[((size_t)b * T_ + tq) * E_ + h2 * D_ + nd * 16 + lr] = f2bf(o[a][nd][r] * inv);
      }
  }
}

// ---------------- launcher ----------------
extern "C" void kernel_launch(void* const* d_in, const int* in_sizes, int n_in,
                              void* d_out, int out_size, void* d_ws, size_t ws_size,
                              hipStream_t stream) {
  const float* x    = (const float*)d_in[0];
  const float* Wq   = (const float*)d_in[1];
  const float* Wk   = (const float*)d_in[2];
  const float* Wv   = (const float*)d_in[3];
  const float* Wout = (const float*)d_in[4];
  const float* bout = (const float*)d_in[5];
  float* out = (float*)d_out;

  const size_t MT = (size_t)B_ * T_;      // 8192
  const size_t XE = MT * E_;              // 8,388,608
  const size_t WE = (size_t)E_ * E_;      // 1,048,576

  size_t need = (XE * 5 + WE * 4) * sizeof(unsigned short);
  if (ws_size < need) return;

  unsigned short* xb  = (unsigned short*)d_ws;
  unsigned short* wqb = xb + XE;
  unsigned short* wkb = wqb + WE;
  unsigned short* wvb = wkb + WE;
  unsigned short* wob = wvb + WE;
  unsigned short* Qb  = wob + WE;
  unsigned short* Kb  = Qb + XE;
  unsigned short* VTb = Kb + XE;
  unsigned short* ctx = VTb + XE;

  cvt_all<<<6144, 256, 0, stream>>>(x, Wq, Wk, Wv, Wout, xb, wqb);

  gemm_qkv2<<<768, 512, 0, stream>>>(xb, wqb, wkb, wvb, Qb, Kb, VTb);

  attn_fused8<<<256, 512, 0, stream>>>(Qb, Kb, VTb, ctx);

  gemm_out2<<<256, 512, 0, stream>>>(ctx, wob, out, bout);
}

// Round 25
// 163.929 us; speedup vs baseline: 1.3724x; 1.0295x over previous
//
#include <hip/hip_runtime.h>
#include <hip/hip_bf16.h>
#include <stdint.h>
#include <math.h>

#define B_ 4
#define T_ 2048
#define E_ 1024
#define H_ 16
#define D_ 64

typedef __attribute__((ext_vector_type(8))) short short8;
typedef __attribute__((ext_vector_type(4))) short short4v;
typedef __attribute__((ext_vector_type(4))) float f32x4;

#define MFMA_BF16(a, b, c) __builtin_amdgcn_mfma_f32_16x16x32_bf16((a), (b), (c), 0, 0, 0)

__device__ __forceinline__ unsigned short f2bf(float f) {
  union { float f; unsigned u; } v; v.f = f;
  unsigned r = v.u + 0x7FFFu + ((v.u >> 16) & 1u);  // RNE
  return (unsigned short)(r >> 16);
}

#define GLOAD_LDS16(g, l)                                                        \
  __builtin_amdgcn_global_load_lds((const __attribute__((address_space(1))) void*)(g), \
                                   (__attribute__((address_space(3))) void*)(l), 16, 0, 0)

// ---------------- fp32 -> bf16 convert: x + 4 weights in ONE launch ----------
__global__ __launch_bounds__(256) void cvt_all(const float* __restrict__ x,
                                               const float* __restrict__ w0,
                                               const float* __restrict__ w1,
                                               const float* __restrict__ w2,
                                               const float* __restrict__ w3,
                                               unsigned short* __restrict__ xb,
                                               unsigned short* __restrict__ wb) {
  const int NX8 = 1048576;  // XE/8
  int i = blockIdx.x * blockDim.x + threadIdx.x;
  const float* src;
  unsigned short* dst;
  size_t off;
  if (i < NX8) {
    src = x; dst = xb; off = (size_t)i * 8;
  } else {
    int j = i - NX8;
    int which = j >> 17;             // WE/8 = 2^17
    int o = j & 131071;
    src = (which == 0) ? w0 : (which == 1) ? w1 : (which == 2) ? w2 : w3;
    dst = wb + ((size_t)which << 20);
    off = (size_t)o * 8;
  }
  const float4* p = (const float4*)(src + off);
  float4 a = p[0], b = p[1];
  short8 r;
  r[0] = (short)f2bf(a.x); r[1] = (short)f2bf(a.y);
  r[2] = (short)f2bf(a.z); r[3] = (short)f2bf(a.w);
  r[4] = (short)f2bf(b.x); r[5] = (short)f2bf(b.y);
  r[6] = (short)f2bf(b.z); r[7] = (short)f2bf(b.w);
  *(short8*)(dst + off) = r;
}

// =============== 128x256 2-phase pipelined GEMM template (r18, proven) =======
#define GEMM2_BODY(A_PTR, B_PTR)                                                  \
  const int K = E_;                                                               \
  const int NT = 16;                                                              \
  const int tid = threadIdx.x;                                                    \
  const int wid = tid >> 6;                                                       \
  const int lane = tid & 63;                                                      \
  const int lr = lane & 15;                                                       \
  const int lk = lane >> 4;                                                       \
  const int wm = wid >> 2, wn = wid & 3;                                          \
  const int srow = lane >> 3;                                                     \
  const int scol = ((lane & 7) ^ srow) * 8;                                       \
  const int rswz = (lr & 7) << 4;                                                 \
  const int kofs0 = (lk * 16) ^ rswz;                                             \
  const int kofs1 = (64 + lk * 16) ^ rswz;                                        \
  f32x4 acc[4][4] = {};                                                           \
  short8 af[4][2], bf0[2][2], bf1[2][2];                                          \
  auto stageA = [&](int tau) {                                                    \
    char* dst = lds + (tau & 1) * 49152 + wid * 1024;                             \
    const unsigned short* src = (A_PTR) + (size_t)(m0 + wid * 8 + srow) * K +     \
                                tau * 64 + scol;                                  \
    GLOAD_LDS16(src, dst);                                                        \
    GLOAD_LDS16(src + (size_t)64 * K, dst + 8192);                                \
  };                                                                              \
  auto stageB = [&](int tau) {                                                    \
    char* dst = lds + (tau & 1) * 49152 + 16384 + wid * 1024;                     \
    const unsigned short* src = (B_PTR) + (size_t)(n0 + wid * 8 + srow) * K +     \
                                tau * 64 + scol;                                  \
    GLOAD_LDS16(src, dst);                                                        \
    GLOAD_LDS16(src + (size_t)64 * K, dst + 8192);                                \
    GLOAD_LDS16(src + (size_t)128 * K, dst + 16384);                              \
    GLOAD_LDS16(src + (size_t)192 * K, dst + 24576);                              \
  };                                                                              \
  stageB(0); stageA(0); stageB(1);                                                \
  asm volatile("s_waitcnt vmcnt(4)" ::: "memory");                                \
  __builtin_amdgcn_s_barrier();                                                   \
  for (int t = 0; t < NT; ++t) {                                                  \
    char* bufA = lds + (t & 1) * 49152;                                           \
    char* bufB = bufA + 16384;                                                    \
    _Pragma("unroll")                                                             \
    for (int i = 0; i < 4; ++i) {                                                 \
      int row = wm * 64 + i * 16 + lr;                                            \
      af[i][0] = *(const short8*)(bufA + row * 128 + kofs0);                      \
      af[i][1] = *(const short8*)(bufA + row * 128 + kofs1);                      \
    }                                                                             \
    _Pragma("unroll")                                                             \
    for (int i = 0; i < 2; ++i) {                                                 \
      int row0 = wn * 64 + i * 16 + lr;                                           \
      int row1 = wn * 64 + (2 + i) * 16 + lr;                                     \
      bf0[i][0] = *(const short8*)(bufB + row0 * 128 + kofs0);                    \
      bf0[i][1] = *(const short8*)(bufB + row0 * 128 + kofs1);                    \
      bf1[i][0] = *(const short8*)(bufB + row1 * 128 + kofs0);                    \
      bf1[i][1] = *(const short8*)(bufB + row1 * 128 + kofs1);                    \
    }                                                                             \
    if (t + 1 < NT) stageA(t + 1);                                                \
    __builtin_amdgcn_s_barrier();                                                 \
    asm volatile("s_waitcnt lgkmcnt(0)" ::: "memory");                            \
    __builtin_amdgcn_sched_barrier(0);                                            \
    __builtin_amdgcn_s_setprio(1);                                                \
    _Pragma("unroll")                                                             \
    for (int i = 0; i < 4; ++i)                                                   \
      _Pragma("unroll")                                                           \
      for (int jn = 0; jn < 2; ++jn) {                                            \
        acc[i][jn] = MFMA_BF16(af[i][0], bf0[jn][0], acc[i][jn]);                 \
        acc[i][jn] = MFMA_BF16(af[i][1], bf0[jn][1], acc[i][jn]);                 \
      }                                                                           \
    __builtin_amdgcn_s_setprio(0);                                                \
    __builtin_amdgcn_s_barrier();                                                 \
    if (t + 2 < NT) stageB(t + 2);                                                \
    __builtin_amdgcn_s_setprio(1);                                                \
    _Pragma("unroll")                                                             \
    for (int i = 0; i < 4; ++i)                                                   \
      _Pragma("unroll")                                                           \
      for (int jn = 0; jn < 2; ++jn) {                                            \
        acc[i][2 + jn] = MFMA_BF16(af[i][0], bf1[jn][0], acc[i][2 + jn]);         \
        acc[i][2 + jn] = MFMA_BF16(af[i][1], bf1[jn][1], acc[i][2 + jn]);         \
      }                                                                           \
    __builtin_amdgcn_s_setprio(0);                                                \
    if (t < NT - 2) asm volatile("s_waitcnt vmcnt(4)" ::: "memory");              \
    else            asm volatile("s_waitcnt vmcnt(0)" ::: "memory");              \
    __builtin_amdgcn_s_barrier();                                                 \
  }

// ---------------- QKV GEMM (768 blocks = 3 exact rounds at 1 blk/CU) ---------
__global__ __launch_bounds__(512) void gemm_qkv2(const unsigned short* __restrict__ A,
                                                 const unsigned short* __restrict__ Wq,
                                                 const unsigned short* __restrict__ Wk,
                                                 const unsigned short* __restrict__ Wv,
                                                 unsigned short* __restrict__ Qo,
                                                 unsigned short* __restrict__ Ko,
                                                 unsigned short* __restrict__ Vo) {
  __shared__ __align__(16) char lds[98304];
  const int bid = blockIdx.x;
  const int xcd = bid & 7;
  const int p = bid >> 3;               // 0..95
  const int m0 = (xcd * 8 + (p & 7)) * 128;
  const int j = p >> 3;                 // 0..11
  const int n0 = (j & 3) * 256;
  const int sel = j >> 2;
  const unsigned short* Bm = (sel == 0) ? Wq : (sel == 1) ? Wk : Wv;

  GEMM2_BODY(A, Bm)

  unsigned short* outp = (sel == 0) ? Qo : (sel == 1) ? Ko : Vo;
#pragma unroll
  for (int mi = 0; mi < 4; ++mi)
#pragma unroll
    for (int ni = 0; ni < 4; ++ni) {
      int row0 = m0 + wm * 64 + mi * 16 + lk * 4;
      int col = n0 + wn * 64 + ni * 16 + lr;
      int b = row0 >> 11, t0 = row0 & (T_ - 1), h = col >> 6, d = col & (D_ - 1);
      if (sel == 2) {
        short4v vv;
#pragma unroll
        for (int r = 0; r < 4; ++r) vv[r] = (short)f2bf(acc[mi][ni][r]);
        *(short4v*)&outp[(((size_t)(b * H_ + h)) * D_ + d) * T_ + t0] = vv;  // [BH][D][T]
      } else {
#pragma unroll
        for (int r = 0; r < 4; ++r)
          outp[(((size_t)(b * H_ + h)) * T_ + t0 + r) * D_ + d] = f2bf(acc[mi][ni][r]);
      }
    }
}

// ---------------- out-proj GEMM (256 blocks = exactly 1/CU) ------------------
__global__ __launch_bounds__(512) void gemm_out2(const unsigned short* __restrict__ A,
                                                 const unsigned short* __restrict__ Wout,
                                                 float* __restrict__ outp,
                                                 const float* __restrict__ bias) {
  __shared__ __align__(16) char lds[98304];
  const int bid = blockIdx.x;
  const int xcd = bid & 7;
  const int p = bid >> 3;               // 0..31
  const int m0 = (xcd * 8 + (p & 7)) * 128;
  const int n0 = (p >> 3) * 256;

  GEMM2_BODY(A, Wout)

#pragma unroll
  for (int mi = 0; mi < 4; ++mi)
#pragma unroll
    for (int ni = 0; ni < 4; ++ni) {
      int row0 = m0 + wm * 64 + mi * 16 + lk * 4;
      int col = n0 + wn * 64 + ni * 16 + lr;
      float bv = bias[col];
#pragma unroll
      for (int r = 0; r < 4; ++r)
        outp[(size_t)(row0 + r) * E_ + col] = acc[mi][ni][r] + bv;
    }
}

// ---------------- fused causal flash attention (8-wave, 128-kv double-tiles) -
// r24 base (256 blocks x 512 thr, intrinsic 36-tile pairing, sigma-register P)
// with TWO kv-tiles per loop iteration: one barrier+drain per 128 kv rows
// (halves the per-tile sync quantum that bound r19-r24 at ~6250 cy/tile);
// the two tiles' QK/softmax chains are data-independent and interleave.
// LDS: 2 x 32KB double-tile buffers.
__global__ __launch_bounds__(512) void attn_fused8(const unsigned short* __restrict__ Q,
                                                   const unsigned short* __restrict__ K,
                                                   const unsigned short* __restrict__ VT,
                                                   unsigned short* __restrict__ ctx) {
  __shared__ __align__(16) char kvb[2][32768];  // [buf][t0: K8K|V8K][t1: K8K|V8K]
  const int tid = threadIdx.x;
  const int wid = tid >> 6;
  const int lane = tid & 63;
  const int lr = lane & 15;
  const int lk = lane >> 4;

  // 256 = 8 xcd x 8 heads x 4 pair-ids
  const int bid = blockIdx.x;
  const int xcd = bid & 7;
  const int p = bid >> 3;            // 0..31
  const int bh = xcd * 8 + (p & 7);
  const int g = p >> 3;              // 0..3

  const unsigned short* Qh = Q + (size_t)bh * T_ * D_;
  const unsigned short* Kh = K + (size_t)bh * T_ * D_;
  const unsigned short* Vh = VT + (size_t)bh * T_ * D_;  // [D][T]

  const float SC = 0.125f * 1.44269504089f;  // 1/sqrt(D) * log2(e)

  // staging: per double-tile, thread stages 16B of K and V for BOTH tiles
  const int srow = tid >> 3;                       // 0..63
  const int scol = ((tid & 7) ^ (srow & 7)) * 8;   // pre-swizzled col (elems)
  const int rswz = (lr & 7) << 4;                  // read-side XOR (bytes)

  auto stage2 = [&](int dt, int bi) {  // stages tiles 2dt, 2dt+1
    char* dst = kvb[bi] + tid * 16;
    const int t0 = 2 * dt, t1 = 2 * dt + 1;
    GLOAD_LDS16(Kh + (size_t)(t0 * 64 + srow) * D_ + scol, dst);
    GLOAD_LDS16(Vh + (size_t)srow * T_ + t0 * 64 + scol, dst + 8192);
    GLOAD_LDS16(Kh + (size_t)(t1 * 64 + srow) * D_ + scol, dst + 16384);
    GLOAD_LDS16(Vh + (size_t)srow * T_ + t1 * 64 + scol, dst + 24576);
  };

  short8 vones;
#pragma unroll
  for (int jj = 0; jj < 8; ++jj) vones[jj] = (short)0x3F80;  // bf16 1.0

  const int b = bh >> 4, h2 = bh & 15;

  for (int pass = 0; pass < 2; ++pass) {
    const int Qb = pass ? g : (7 - g);
    const int q0w = Qb * 256 + wid * 32;
    const int diag = q0w >> 6;       // wave's diagonal kv-tile
    const int ql0 = (wid & 1) * 32;  // q-local base within diag tile
    const int NTd = 2 * Qb + 2;      // double-tile trip count ((4Qb+4)/2)

    // Q as B-operand: col=q=lr, k=d
    short8 qf[2][2];
#pragma unroll
    for (int a = 0; a < 2; ++a)
#pragma unroll
      for (int kb = 0; kb < 2; ++kb)
        qf[a][kb] = *(const short8*)&Qh[(size_t)(q0w + a * 16 + lr) * D_ + kb * 32 + lk * 8];

    f32x4 o[2][4] = {};
    f32x4 lsum[2] = {};
    float mrun[2] = {-1e30f, -1e30f};

    // one-tile compute from LDS section at base kv_
    auto tileC = [&](const char* kv_, int t) {
      const char* kb_ = kv_;
      const char* vb_ = kv_ + 8192;

      short8 kf[2][4];
#pragma unroll
      for (int kb = 0; kb < 2; ++kb)
#pragma unroll
        for (int n = 0; n < 4; ++n)
          kf[kb][n] = *(const short8*)(kb_ + (n * 16 + lr) * 128 + ((kb * 64 + lk * 16) ^ rswz));

      short8 vreg[2][4];
#pragma unroll
      for (int h = 0; h < 2; ++h)
#pragma unroll
        for (int nd = 0; nd < 4; ++nd) {
          const char* vrow = vb_ + (nd * 16 + lr) * 128;
          *(uint2*)&vreg[h][nd] = *(const uint2*)(vrow + ((h * 64 + lk * 8) ^ rswz));
          *((uint2*)&vreg[h][nd] + 1) = *(const uint2*)(vrow + ((h * 64 + 32 + lk * 8) ^ rswz));
        }

      f32x4 st[2][4] = {};
#pragma unroll
      for (int kb = 0; kb < 2; ++kb)
#pragma unroll
        for (int a = 0; a < 2; ++a)
#pragma unroll
          for (int n = 0; n < 4; ++n)
            st[a][n] = MFMA_BF16(kf[kb][n], qf[a][kb], st[a][n]);

      if (t == diag) {  // causal mask
#pragma unroll
        for (int a = 0; a < 2; ++a)
#pragma unroll
          for (int n = 0; n < 4; ++n)
#pragma unroll
            for (int r = 0; r < 4; ++r)
              if (n * 16 + lk * 4 + r > ql0 + a * 16 + lr) st[a][n][r] = -3e38f;
      }

      float pm[2];
#pragma unroll
      for (int a = 0; a < 2; ++a) {
        float m0 = fmaxf(fmaxf(st[a][0][0], st[a][1][0]), fmaxf(st[a][2][0], st[a][3][0]));
        float m1 = fmaxf(fmaxf(st[a][0][1], st[a][1][1]), fmaxf(st[a][2][1], st[a][3][1]));
        float m2 = fmaxf(fmaxf(st[a][0][2], st[a][1][2]), fmaxf(st[a][2][2], st[a][3][2]));
        float m3 = fmaxf(fmaxf(st[a][0][3], st[a][1][3]), fmaxf(st[a][2][3], st[a][3][3]));
        float mx = fmaxf(fmaxf(m0, m1), fmaxf(m2, m3));
        mx = fmaxf(mx, __shfl_xor(mx, 16));
        mx = fmaxf(mx, __shfl_xor(mx, 32));
        pm[a] = mx * SC;
      }
      float need = fmaxf(pm[0] - mrun[0], pm[1] - mrun[1]);

      if (__any(need > 8.f)) {  // defer-max rescale (rare)
#pragma unroll
        for (int a = 0; a < 2; ++a) {
          float mnew = fmaxf(mrun[a], pm[a]);
          float sc = exp2f(mrun[a] - mnew);
          mrun[a] = mnew;
#pragma unroll
          for (int r = 0; r < 4; ++r) {
            float sco = __shfl(sc, (lane & 48) | (lk * 4 + r));
            lsum[a][r] *= sco;
#pragma unroll
            for (int nd = 0; nd < 4; ++nd) o[a][nd][r] *= sco;
          }
        }
      }

      short8 pf[2][2];
#pragma unroll
      for (int a = 0; a < 2; ++a) {
        f32x4 pt[4];
#pragma unroll
        for (int n = 0; n < 4; ++n)
#pragma unroll
          for (int r = 0; r < 4; ++r)
            pt[n][r] = exp2f(fmaf(st[a][n][r], SC, -mrun[a]));
#pragma unroll
        for (int h = 0; h < 2; ++h) {
          float2 x01, x23, y01, y23;
          x01.x = pt[2 * h][0];     x01.y = pt[2 * h][1];
          x23.x = pt[2 * h][2];     x23.y = pt[2 * h][3];
          y01.x = pt[2 * h + 1][0]; y01.y = pt[2 * h + 1][1];
          y23.x = pt[2 * h + 1][2]; y23.y = pt[2 * h + 1][3];
          __hip_bfloat162 b0 = __float22bfloat162_rn(x01);
          __hip_bfloat162 b1 = __float22bfloat162_rn(x23);
          __hip_bfloat162 b2 = __float22bfloat162_rn(y01);
          __hip_bfloat162 b3 = __float22bfloat162_rn(y23);
          unsigned* w = (unsigned*)&pf[a][h];
          w[0] = *(unsigned*)&b0;
          w[1] = *(unsigned*)&b1;
          w[2] = *(unsigned*)&b2;
          w[3] = *(unsigned*)&b3;
        }
      }

#pragma unroll
      for (int h = 0; h < 2; ++h) {
#pragma unroll
        for (int nd = 0; nd < 4; ++nd) {
          o[0][nd] = MFMA_BF16(pf[0][h], vreg[h][nd], o[0][nd]);
          o[1][nd] = MFMA_BF16(pf[1][h], vreg[h][nd], o[1][nd]);
        }
        lsum[0] = MFMA_BF16(pf[0][h], vones, lsum[0]);
        lsum[1] = MFMA_BF16(pf[1][h], vones, lsum[1]);
      }
    };

    stage2(0, 0);
    asm volatile("s_waitcnt vmcnt(0)" ::: "memory");
    __builtin_amdgcn_s_barrier();

    for (int dt = 0; dt < NTd; ++dt) {
      if (dt + 1 < NTd) stage2(dt + 1, (dt & 1) ^ 1);  // other parity buffer

      const char* base = kvb[dt & 1];
      const int t0 = 2 * dt, t1 = 2 * dt + 1;
      if (t0 <= diag) tileC(base, t0);
      if (t1 <= diag) tileC(base + 16384, t1);

      asm volatile("s_waitcnt vmcnt(0)" ::: "memory");  // next stage landed
      __builtin_amdgcn_s_barrier();
    }

#pragma unroll
    for (int a = 0; a < 2; ++a)
#pragma unroll
      for (int r = 0; r < 4; ++r) {
        float inv = 1.0f / lsum[a][r];
        int tq = q0w + a * 16 + lk * 4 + r;
#pragma unroll
        for (int nd = 0; nd < 4; ++nd)
          ctx[((size_t)b * T_ + tq) * E_ + h2 * D_ + nd * 16 + lr] = f2bf(o[a][nd][r] * inv);
      }
  }
}

// ---------------- launcher ----------------
extern "C" void kernel_launch(void* const* d_in, const int* in_sizes, int n_in,
                              void* d_out, int out_size, void* d_ws, size_t ws_size,
                              hipStream_t stream) {
  const float* x    = (const float*)d_in[0];
  const float* Wq   = (const float*)d_in[1];
  const float* Wk   = (const float*)d_in[2];
  const float* Wv   = (const float*)d_in[3];
  const float* Wout = (const float*)d_in[4];
  const float* bout = (const float*)d_in[5];
  float* out = (float*)d_out;

  const size_t MT = (size_t)B_ * T_;      // 8192
  const size_t XE = MT * E_;              // 8,388,608
  const size_t WE = (size_t)E_ * E_;      // 1,048,576

  size_t need = (XE * 5 + WE * 4) * sizeof(unsigned short);
  if (ws_size < need) return;

  unsigned short* xb  = (unsigned short*)d_ws;
  unsigned short* wqb = xb + XE;
  unsigned short* wkb = wqb + WE;
  unsigned short* wvb = wkb + WE;
  unsigned short* wob = wvb + WE;
  unsigned short* Qb  = wob + WE;
  unsigned short* Kb  = Qb + XE;
  unsigned short* VTb = Kb + XE;
  unsigned short* ctx = VTb + XE;

  cvt_all<<<6144, 256, 0, stream>>>(x, Wq, Wk, Wv, Wout, xb, wqb);

  gemm_qkv2<<<768, 512, 0, stream>>>(xb, wqb, wkb, wvb, Qb, Kb, VTb);

  attn_fused8<<<256, 512, 0, stream>>>(Qb, Kb, VTb, ctx);

  gemm_out2<<<256, 512, 0, stream>>>(ctx, wob, out, bout);
}

// Round 26
// 160.780 us; speedup vs baseline: 1.3993x; 1.0196x over previous
//
#include <hip/hip_runtime.h>
#include <hip/hip_bf16.h>
#include <stdint.h>
#include <math.h>

#define B_ 4
#define T_ 2048
#define E_ 1024
#define H_ 16
#define D_ 64

typedef __attribute__((ext_vector_type(8))) short short8;
typedef __attribute__((ext_vector_type(4))) short short4v;
typedef __attribute__((ext_vector_type(4))) float f32x4;

#define MFMA_BF16(a, b, c) __builtin_amdgcn_mfma_f32_16x16x32_bf16((a), (b), (c), 0, 0, 0)

__device__ __forceinline__ unsigned short f2bf(float f) {
  union { float f; unsigned u; } v; v.f = f;
  unsigned r = v.u + 0x7FFFu + ((v.u >> 16) & 1u);  // RNE
  return (unsigned short)(r >> 16);
}

#define GLOAD_LDS16(g, l)                                                        \
  __builtin_amdgcn_global_load_lds((const __attribute__((address_space(1))) void*)(g), \
                                   (__attribute__((address_space(3))) void*)(l), 16, 0, 0)

// ---------------- fp32 -> bf16 convert: x + 4 weights in ONE launch ----------
__global__ __launch_bounds__(256) void cvt_all(const float* __restrict__ x,
                                               const float* __restrict__ w0,
                                               const float* __restrict__ w1,
                                               const float* __restrict__ w2,
                                               const float* __restrict__ w3,
                                               unsigned short* __restrict__ xb,
                                               unsigned short* __restrict__ wb) {
  const int NX8 = 1048576;  // XE/8
  int i = blockIdx.x * blockDim.x + threadIdx.x;
  const float* src;
  unsigned short* dst;
  size_t off;
  if (i < NX8) {
    src = x; dst = xb; off = (size_t)i * 8;
  } else {
    int j = i - NX8;
    int which = j >> 17;             // WE/8 = 2^17
    int o = j & 131071;
    src = (which == 0) ? w0 : (which == 1) ? w1 : (which == 2) ? w2 : w3;
    dst = wb + ((size_t)which << 20);
    off = (size_t)o * 8;
  }
  const float4* p = (const float4*)(src + off);
  float4 a = p[0], b = p[1];
  short8 r;
  r[0] = (short)f2bf(a.x); r[1] = (short)f2bf(a.y);
  r[2] = (short)f2bf(a.z); r[3] = (short)f2bf(a.w);
  r[4] = (short)f2bf(b.x); r[5] = (short)f2bf(b.y);
  r[6] = (short)f2bf(b.z); r[7] = (short)f2bf(b.w);
  *(short8*)(dst + off) = r;
}

// =============== 128x256 2-phase pipelined GEMM template (r18, proven) =======
#define GEMM2_BODY(A_PTR, B_PTR)                                                  \
  const int K = E_;                                                               \
  const int NT = 16;                                                              \
  const int tid = threadIdx.x;                                                    \
  const int wid = tid >> 6;                                                       \
  const int lane = tid & 63;                                                      \
  const int lr = lane & 15;                                                       \
  const int lk = lane >> 4;                                                       \
  const int wm = wid >> 2, wn = wid & 3;                                          \
  const int srow = lane >> 3;                                                     \
  const int scol = ((lane & 7) ^ srow) * 8;                                       \
  const int rswz = (lr & 7) << 4;                                                 \
  const int kofs0 = (lk * 16) ^ rswz;                                             \
  const int kofs1 = (64 + lk * 16) ^ rswz;                                        \
  f32x4 acc[4][4] = {};                                                           \
  short8 af[4][2], bf0[2][2], bf1[2][2];                                          \
  auto stageA = [&](int tau) {                                                    \
    char* dst = lds + (tau & 1) * 49152 + wid * 1024;                             \
    const unsigned short* src = (A_PTR) + (size_t)(m0 + wid * 8 + srow) * K +     \
                                tau * 64 + scol;                                  \
    GLOAD_LDS16(src, dst);                                                        \
    GLOAD_LDS16(src + (size_t)64 * K, dst + 8192);                                \
  };                                                                              \
  auto stageB = [&](int tau) {                                                    \
    char* dst = lds + (tau & 1) * 49152 + 16384 + wid * 1024;                     \
    const unsigned short* src = (B_PTR) + (size_t)(n0 + wid * 8 + srow) * K +     \
                                tau * 64 + scol;                                  \
    GLOAD_LDS16(src, dst);                                                        \
    GLOAD_LDS16(src + (size_t)64 * K, dst + 8192);                                \
    GLOAD_LDS16(src + (size_t)128 * K, dst + 16384);                              \
    GLOAD_LDS16(src + (size_t)192 * K, dst + 24576);                              \
  };                                                                              \
  stageB(0); stageA(0); stageB(1);                                                \
  asm volatile("s_waitcnt vmcnt(4)" ::: "memory");                                \
  __builtin_amdgcn_s_barrier();                                                   \
  for (int t = 0; t < NT; ++t) {                                                  \
    char* bufA = lds + (t & 1) * 49152;                                           \
    char* bufB = bufA + 16384;                                                    \
    _Pragma("unroll")                                                             \
    for (int i = 0; i < 4; ++i) {                                                 \
      int row = wm * 64 + i * 16 + lr;                                            \
      af[i][0] = *(const short8*)(bufA + row * 128 + kofs0);                      \
      af[i][1] = *(const short8*)(bufA + row * 128 + kofs1);                      \
    }                                                                             \
    _Pragma("unroll")                                                             \
    for (int i = 0; i < 2; ++i) {                                                 \
      int row0 = wn * 64 + i * 16 + lr;                                           \
      int row1 = wn * 64 + (2 + i) * 16 + lr;                                     \
      bf0[i][0] = *(const short8*)(bufB + row0 * 128 + kofs0);                    \
      bf0[i][1] = *(const short8*)(bufB + row0 * 128 + kofs1);                    \
      bf1[i][0] = *(const short8*)(bufB + row1 * 128 + kofs0);                    \
      bf1[i][1] = *(const short8*)(bufB + row1 * 128 + kofs1);                    \
    }                                                                             \
    if (t + 1 < NT) stageA(t + 1);                                                \
    __builtin_amdgcn_s_barrier();                                                 \
    asm volatile("s_waitcnt lgkmcnt(0)" ::: "memory");                            \
    __builtin_amdgcn_sched_barrier(0);                                            \
    __builtin_amdgcn_s_setprio(1);                                                \
    _Pragma("unroll")                                                             \
    for (int i = 0; i < 4; ++i)                                                   \
      _Pragma("unroll")                                                           \
      for (int jn = 0; jn < 2; ++jn) {                                            \
        acc[i][jn] = MFMA_BF16(af[i][0], bf0[jn][0], acc[i][jn]);                 \
        acc[i][jn] = MFMA_BF16(af[i][1], bf0[jn][1], acc[i][jn]);                 \
      }                                                                           \
    __builtin_amdgcn_s_setprio(0);                                                \
    __builtin_amdgcn_s_barrier();                                                 \
    if (t + 2 < NT) stageB(t + 2);                                                \
    __builtin_amdgcn_s_setprio(1);                                                \
    _Pragma("unroll")                                                             \
    for (int i = 0; i < 4; ++i)                                                   \
      _Pragma("unroll")                                                           \
      for (int jn = 0; jn < 2; ++jn) {                                            \
        acc[i][2 + jn] = MFMA_BF16(af[i][0], bf1[jn][0], acc[i][2 + jn]);         \
        acc[i][2 + jn] = MFMA_BF16(af[i][1], bf1[jn][1], acc[i][2 + jn]);         \
      }                                                                           \
    __builtin_amdgcn_s_setprio(0);                                                \
    if (t < NT - 2) asm volatile("s_waitcnt vmcnt(4)" ::: "memory");              \
    else            asm volatile("s_waitcnt vmcnt(0)" ::: "memory");              \
    __builtin_amdgcn_s_barrier();                                                 \
  }

// ---------------- QKV GEMM (768 blocks = 3 exact rounds at 1 blk/CU) ---------
__global__ __launch_bounds__(512) void gemm_qkv2(const unsigned short* __restrict__ A,
                                                 const unsigned short* __restrict__ Wq,
                                                 const unsigned short* __restrict__ Wk,
                                                 const unsigned short* __restrict__ Wv,
                                                 unsigned short* __restrict__ Qo,
                                                 unsigned short* __restrict__ Ko,
                                                 unsigned short* __restrict__ Vo) {
  __shared__ __align__(16) char lds[98304];
  const int bid = blockIdx.x;
  const int xcd = bid & 7;
  const int p = bid >> 3;               // 0..95
  const int m0 = (xcd * 8 + (p & 7)) * 128;
  const int j = p >> 3;                 // 0..11
  const int n0 = (j & 3) * 256;
  const int sel = j >> 2;
  const unsigned short* Bm = (sel == 0) ? Wq : (sel == 1) ? Wk : Wv;

  GEMM2_BODY(A, Bm)

  unsigned short* outp = (sel == 0) ? Qo : (sel == 1) ? Ko : Vo;
#pragma unroll
  for (int mi = 0; mi < 4; ++mi)
#pragma unroll
    for (int ni = 0; ni < 4; ++ni) {
      int row0 = m0 + wm * 64 + mi * 16 + lk * 4;
      int col = n0 + wn * 64 + ni * 16 + lr;
      int b = row0 >> 11, t0 = row0 & (T_ - 1), h = col >> 6, d = col & (D_ - 1);
      if (sel == 2) {
        short4v vv;
#pragma unroll
        for (int r = 0; r < 4; ++r) vv[r] = (short)f2bf(acc[mi][ni][r]);
        *(short4v*)&outp[(((size_t)(b * H_ + h)) * D_ + d) * T_ + t0] = vv;  // [BH][D][T]
      } else {
#pragma unroll
        for (int r = 0; r < 4; ++r)
          outp[(((size_t)(b * H_ + h)) * T_ + t0 + r) * D_ + d] = f2bf(acc[mi][ni][r]);
      }
    }
}

// ---------------- out-proj GEMM (256 blocks = exactly 1/CU) ------------------
__global__ __launch_bounds__(512) void gemm_out2(const unsigned short* __restrict__ A,
                                                 const unsigned short* __restrict__ Wout,
                                                 float* __restrict__ outp,
                                                 const float* __restrict__ bias) {
  __shared__ __align__(16) char lds[98304];
  const int bid = blockIdx.x;
  const int xcd = bid & 7;
  const int p = bid >> 3;               // 0..31
  const int m0 = (xcd * 8 + (p & 7)) * 128;
  const int n0 = (p >> 3) * 256;

  GEMM2_BODY(A, Wout)

#pragma unroll
  for (int mi = 0; mi < 4; ++mi)
#pragma unroll
    for (int ni = 0; ni < 4; ++ni) {
      int row0 = m0 + wm * 64 + mi * 16 + lk * 4;
      int col = n0 + wn * 64 + ni * 16 + lr;
      float bv = bias[col];
#pragma unroll
      for (int r = 0; r < 4; ++r)
        outp[(size_t)(row0 + r) * E_ + col] = acc[mi][ni][r] + bv;
    }
}

// ---------------- fused causal flash attention (8-wave, 256-kv quad-tiles) ---
// r25 direction, one more step: FOUR kv-tiles per loop iteration -> one
// barrier+drain per 256 kv rows (1/4 of r24's sync rate; r24->r25 halving
// bought 4.3us). LDS: 2 x 64KB quad buffers = 128KB (1 block/CU as before).
// Per pass: quads = Qb+1 exactly; block total = 9 quads (intrinsic balance).
// Body = r22 sigma-register P (proven, no LDS P traffic).
__global__ __launch_bounds__(512) void attn_fused8(const unsigned short* __restrict__ Q,
                                                   const unsigned short* __restrict__ K,
                                                   const unsigned short* __restrict__ VT,
                                                   unsigned short* __restrict__ ctx) {
  __shared__ __align__(16) char kvb[2][65536];  // [buf][4 x (K 8K | V 8K)]
  const int tid = threadIdx.x;
  const int wid = tid >> 6;
  const int lane = tid & 63;
  const int lr = lane & 15;
  const int lk = lane >> 4;

  // 256 = 8 xcd x 8 heads x 4 pair-ids
  const int bid = blockIdx.x;
  const int xcd = bid & 7;
  const int p = bid >> 3;            // 0..31
  const int bh = xcd * 8 + (p & 7);
  const int g = p >> 3;              // 0..3

  const unsigned short* Qh = Q + (size_t)bh * T_ * D_;
  const unsigned short* Kh = K + (size_t)bh * T_ * D_;
  const unsigned short* Vh = VT + (size_t)bh * T_ * D_;  // [D][T]

  const float SC = 0.125f * 1.44269504089f;  // 1/sqrt(D) * log2(e)

  // staging: per quad-tile, thread stages 16B of K and V for FOUR tiles
  const int srow = tid >> 3;                       // 0..63
  const int scol = ((tid & 7) ^ (srow & 7)) * 8;   // pre-swizzled col (elems)
  const int rswz = (lr & 7) << 4;                  // read-side XOR (bytes)

  auto stage4 = [&](int qt, int bi) {  // stages tiles 4qt .. 4qt+3
    char* dst = kvb[bi] + tid * 16;
#pragma unroll
    for (int i = 0; i < 4; ++i) {
      const int t = 4 * qt + i;
      GLOAD_LDS16(Kh + (size_t)(t * 64 + srow) * D_ + scol, dst + i * 16384);
      GLOAD_LDS16(Vh + (size_t)srow * T_ + t * 64 + scol, dst + i * 16384 + 8192);
    }
  };

  short8 vones;
#pragma unroll
  for (int jj = 0; jj < 8; ++jj) vones[jj] = (short)0x3F80;  // bf16 1.0

  const int b = bh >> 4, h2 = bh & 15;

  for (int pass = 0; pass < 2; ++pass) {
    const int Qb = pass ? g : (7 - g);
    const int q0w = Qb * 256 + wid * 32;
    const int diag = q0w >> 6;       // wave's diagonal kv-tile
    const int ql0 = (wid & 1) * 32;  // q-local base within diag tile
    const int NTq = Qb + 1;          // quad-tile trip count ((4Qb+4)/4)

    // Q as B-operand: col=q=lr, k=d
    short8 qf[2][2];
#pragma unroll
    for (int a = 0; a < 2; ++a)
#pragma unroll
      for (int kb = 0; kb < 2; ++kb)
        qf[a][kb] = *(const short8*)&Qh[(size_t)(q0w + a * 16 + lr) * D_ + kb * 32 + lk * 8];

    f32x4 o[2][4] = {};
    f32x4 lsum[2] = {};
    float mrun[2] = {-1e30f, -1e30f};

    // one-tile compute from LDS section at base kv_
    auto tileC = [&](const char* kv_, int t) {
      const char* kb_ = kv_;
      const char* vb_ = kv_ + 8192;

      short8 kf[2][4];
#pragma unroll
      for (int kb = 0; kb < 2; ++kb)
#pragma unroll
        for (int n = 0; n < 4; ++n)
          kf[kb][n] = *(const short8*)(kb_ + (n * 16 + lr) * 128 + ((kb * 64 + lk * 16) ^ rswz));

      short8 vreg[2][4];
#pragma unroll
      for (int h = 0; h < 2; ++h)
#pragma unroll
        for (int nd = 0; nd < 4; ++nd) {
          const char* vrow = vb_ + (nd * 16 + lr) * 128;
          *(uint2*)&vreg[h][nd] = *(const uint2*)(vrow + ((h * 64 + lk * 8) ^ rswz));
          *((uint2*)&vreg[h][nd] + 1) = *(const uint2*)(vrow + ((h * 64 + 32 + lk * 8) ^ rswz));
        }

      f32x4 st[2][4] = {};
#pragma unroll
      for (int kb = 0; kb < 2; ++kb)
#pragma unroll
        for (int a = 0; a < 2; ++a)
#pragma unroll
          for (int n = 0; n < 4; ++n)
            st[a][n] = MFMA_BF16(kf[kb][n], qf[a][kb], st[a][n]);

      if (t == diag) {  // causal mask
#pragma unroll
        for (int a = 0; a < 2; ++a)
#pragma unroll
          for (int n = 0; n < 4; ++n)
#pragma unroll
            for (int r = 0; r < 4; ++r)
              if (n * 16 + lk * 4 + r > ql0 + a * 16 + lr) st[a][n][r] = -3e38f;
      }

      float pm[2];
#pragma unroll
      for (int a = 0; a < 2; ++a) {
        float m0 = fmaxf(fmaxf(st[a][0][0], st[a][1][0]), fmaxf(st[a][2][0], st[a][3][0]));
        float m1 = fmaxf(fmaxf(st[a][0][1], st[a][1][1]), fmaxf(st[a][2][1], st[a][3][1]));
        float m2 = fmaxf(fmaxf(st[a][0][2], st[a][1][2]), fmaxf(st[a][2][2], st[a][3][2]));
        float m3 = fmaxf(fmaxf(st[a][0][3], st[a][1][3]), fmaxf(st[a][2][3], st[a][3][3]));
        float mx = fmaxf(fmaxf(m0, m1), fmaxf(m2, m3));
        mx = fmaxf(mx, __shfl_xor(mx, 16));
        mx = fmaxf(mx, __shfl_xor(mx, 32));
        pm[a] = mx * SC;
      }
      float need = fmaxf(pm[0] - mrun[0], pm[1] - mrun[1]);

      if (__any(need > 8.f)) {  // defer-max rescale (rare)
#pragma unroll
        for (int a = 0; a < 2; ++a) {
          float mnew = fmaxf(mrun[a], pm[a]);
          float sc = exp2f(mrun[a] - mnew);
          mrun[a] = mnew;
#pragma unroll
          for (int r = 0; r < 4; ++r) {
            float sco = __shfl(sc, (lane & 48) | (lk * 4 + r));
            lsum[a][r] *= sco;
#pragma unroll
            for (int nd = 0; nd < 4; ++nd) o[a][nd][r] *= sco;
          }
        }
      }

      short8 pf[2][2];
#pragma unroll
      for (int a = 0; a < 2; ++a) {
        f32x4 pt[4];
#pragma unroll
        for (int n = 0; n < 4; ++n)
#pragma unroll
          for (int r = 0; r < 4; ++r)
            pt[n][r] = exp2f(fmaf(st[a][n][r], SC, -mrun[a]));
#pragma unroll
        for (int h = 0; h < 2; ++h) {
          float2 x01, x23, y01, y23;
          x01.x = pt[2 * h][0];     x01.y = pt[2 * h][1];
          x23.x = pt[2 * h][2];     x23.y = pt[2 * h][3];
          y01.x = pt[2 * h + 1][0]; y01.y = pt[2 * h + 1][1];
          y23.x = pt[2 * h + 1][2]; y23.y = pt[2 * h + 1][3];
          __hip_bfloat162 b0 = __float22bfloat162_rn(x01);
          __hip_bfloat162 b1 = __float22bfloat162_rn(x23);
          __hip_bfloat162 b2 = __float22bfloat162_rn(y01);
          __hip_bfloat162 b3 = __float22bfloat162_rn(y23);
          unsigned* w = (unsigned*)&pf[a][h];
          w[0] = *(unsigned*)&b0;
          w[1] = *(unsigned*)&b1;
          w[2] = *(unsigned*)&b2;
          w[3] = *(unsigned*)&b3;
        }
      }

#pragma unroll
      for (int h = 0; h < 2; ++h) {
#pragma unroll
        for (int nd = 0; nd < 4; ++nd) {
          o[0][nd] = MFMA_BF16(pf[0][h], vreg[h][nd], o[0][nd]);
          o[1][nd] = MFMA_BF16(pf[1][h], vreg[h][nd], o[1][nd]);
        }
        lsum[0] = MFMA_BF16(pf[0][h], vones, lsum[0]);
        lsum[1] = MFMA_BF16(pf[1][h], vones, lsum[1]);
      }
    };

    stage4(0, 0);
    asm volatile("s_waitcnt vmcnt(0)" ::: "memory");
    __builtin_amdgcn_s_barrier();

    for (int qt = 0; qt < NTq; ++qt) {
      if (qt + 1 < NTq) stage4(qt + 1, (qt & 1) ^ 1);  // other parity buffer

      const char* base = kvb[qt & 1];
#pragma unroll
      for (int i = 0; i < 4; ++i) {
        const int t = 4 * qt + i;
        if (t <= diag) tileC(base + i * 16384, t);
      }

      asm volatile("s_waitcnt vmcnt(0)" ::: "memory");  // next stage landed
      __builtin_amdgcn_s_barrier();
    }

#pragma unroll
    for (int a = 0; a < 2; ++a)
#pragma unroll
      for (int r = 0; r < 4; ++r) {
        float inv = 1.0f / lsum[a][r];
        int tq = q0w + a * 16 + lk * 4 + r;
#pragma unroll
        for (int nd = 0; nd < 4; ++nd)
          ctx[((size_t)b * T_ + tq) * E_ + h2 * D_ + nd * 16 + lr] = f2bf(o[a][nd][r] * inv);
      }
  }
}

// ---------------- launcher ----------------
extern "C" void kernel_launch(void* const* d_in, const int* in_sizes, int n_in,
                              void* d_out, int out_size, void* d_ws, size_t ws_size,
                              hipStream_t stream) {
  const float* x    = (const float*)d_in[0];
  const float* Wq   = (const float*)d_in[1];
  const float* Wk   = (const float*)d_in[2];
  const float* Wv   = (const float*)d_in[3];
  const float* Wout = (const float*)d_in[4];
  const float* bout = (const float*)d_in[5];
  float* out = (float*)d_out;

  const size_t MT = (size_t)B_ * T_;      // 8192
  const size_t XE = MT * E_;              // 8,388,608
  const size_t WE = (size_t)E_ * E_;      // 1,048,576

  size_t need = (XE * 5 + WE * 4) * sizeof(unsigned short);
  if (ws_size < need) return;

  unsigned short* xb  = (unsigned short*)d_ws;
  unsigned short* wqb = xb + XE;
  unsigned short* wkb = wqb + WE;
  unsigned short* wvb = wkb + WE;
  unsigned short* wob = wvb + WE;
  unsigned short* Qb  = wob + WE;
  unsigned short* Kb  = Qb + XE;
  unsigned short* VTb = Kb + XE;
  unsigned short* ctx = VTb + XE;

  cvt_all<<<6144, 256, 0, stream>>>(x, Wq, Wk, Wv, Wout, xb, wqb);

  gemm_qkv2<<<768, 512, 0, stream>>>(xb, wqb, wkb, wvb, Qb, Kb, VTb);

  attn_fused8<<<256, 512, 0, stream>>>(Qb, Kb, VTb, ctx);

  gemm_out2<<<256, 512, 0, stream>>>(ctx, wob, out, bout);
}